// Round 1
// baseline (894.027 us; speedup 1.0000x reference)
//
#include <hip/hip_runtime.h>
#include <math.h>

#define B_TOTAL 2048
#define T_LEN   512
#define IN_D    6
#define HID     64
#define LAT     16
#define ROWS    2        // batch rows per block
#define THREADS 128      // 2 waves: wave w covers j = w*32 .. w*32+31, each j split over kq=0/1 k-halves

__device__ __forceinline__ float fast_sigmoid(float x){
    float e = __expf(-x);
    return __fdividef(1.0f, 1.0f + e);
}
__device__ __forceinline__ float fast_tanh(float x){
    float e = __expf(2.0f * x);                 // inf for large x is fine: 2/inf -> 0
    return 1.0f - __fdividef(2.0f, e + 1.0f);
}

extern "C" __global__ __launch_bounds__(THREADS, 2)
void glsde_kernel(const float* __restrict__ x,
                  const float* __restrict__ eWih, const float* __restrict__ eWhh,
                  const float* __restrict__ ebih, const float* __restrict__ ebhh,
                  const float* __restrict__ muW,  const float* __restrict__ mub,
                  const float* __restrict__ lvW,  const float* __restrict__ lvb,
                  const float* __restrict__ oW,   const float* __restrict__ ob,
                  const float* __restrict__ dfW,  const float* __restrict__ dfb,
                  const float* __restrict__ dWih, const float* __restrict__ dWhh,
                  const float* __restrict__ dbih, const float* __restrict__ dbhh,
                  float* __restrict__ out)
{
    __shared__ float hbuf[2][ROWS][HID];     // double-buffered hidden state
    __shared__ float xsh[2][ROWS][IN_D];     // double-buffered x(t)
    __shared__ float zsh[ROWS][LAT];
    __shared__ float zdsh[ROWS][HID];
    __shared__ float xgdsh[ROWS][3];
    __shared__ float outsh[ROWS][T_LEN];

    const int tid  = threadIdx.x;
    const int wv   = tid >> 6;        // wave 0/1
    const int lane = tid & 63;
    const int jl   = lane & 31;
    const int kq   = lane >> 5;       // k-half 0/1 within wave
    const int j    = wv * 32 + jl;    // hidden unit 0..63
    const int b0   = blockIdx.x * ROWS;

    // ---- recurrent weights -> registers (never touch LDS again) ----
    // lane (j, kq) owns Whh rows {j, 64+j, 128+j}, cols [kq*32, kq*32+32)
    float4 Wr4[8], Wz4[8], Wn4[8];
    {
        const float4* pr = (const float4*)(eWhh + (size_t)(      j) * HID + kq * 32);
        const float4* pz = (const float4*)(eWhh + (size_t)( 64 + j) * HID + kq * 32);
        const float4* pn = (const float4*)(eWhh + (size_t)(128 + j) * HID + kq * 32);
        #pragma unroll
        for (int q = 0; q < 8; ++q){ Wr4[q] = pr[q]; Wz4[q] = pz[q]; Wn4[q] = pn[q]; }
    }
    // input-side weights: kq=0 handles x dims 0..2, kq=1 handles 3..5
    const int d0 = kq * 3;
    float Wxr[3], Wxz[3], Wxn[3];
    #pragma unroll
    for (int dd = 0; dd < 3; ++dd){
        Wxr[dd] = eWih[(size_t)(      j) * IN_D + d0 + dd];
        Wxz[dd] = eWih[(size_t)( 64 + j) * IN_D + d0 + dd];
        Wxn[dd] = eWih[(size_t)(128 + j) * IN_D + d0 + dd];
    }
    const float bias_r = ebih[j]       + ebhh[j];
    const float bias_z = ebih[64 + j]  + ebhh[64 + j];
    const float bihn   = ebih[128 + j];
    const float bhhn   = ebhh[128 + j];

    // ---- init h=0 and x(t=0) ----
    if (tid < ROWS * HID) hbuf[0][tid >> 6][tid & 63] = 0.0f;
    const int xrow = tid / IN_D, xd = tid % IN_D;
    if (tid < ROWS * IN_D)
        xsh[0][xrow][xd] = x[((size_t)(b0 + xrow) * T_LEN + 0) * IN_D + xd];
    __syncthreads();

    // ================= encoder GRU: 512 sequential steps =================
    int cb = 0;
    for (int t = 0; t < T_LEN; ++t){
        // prefetch x(t+1) into a register (global latency hidden under FMA issue)
        float xpre = 0.0f;
        if (tid < ROWS * IN_D){
            int tn = (t + 1 < T_LEN) ? (t + 1) : (T_LEN - 1);
            xpre = x[((size_t)(b0 + xrow) * T_LEN + tn) * IN_D + xd];
        }

        float ar[ROWS], az[ROWS], ahn[ROWS], axn[ROWS];
        #pragma unroll
        for (int r = 0; r < ROWS; ++r){
            float a_r = 0.f, a_z = 0.f, a_hn = 0.f, a_xn = 0.f;
            const float4* hp = (const float4*)(&hbuf[cb][r][kq * 32]);
            #pragma unroll
            for (int q = 0; q < 8; ++q){
                float4 h4 = hp[q];
                a_r  += Wr4[q].x*h4.x + Wr4[q].y*h4.y + Wr4[q].z*h4.z + Wr4[q].w*h4.w;
                a_z  += Wz4[q].x*h4.x + Wz4[q].y*h4.y + Wz4[q].z*h4.z + Wz4[q].w*h4.w;
                a_hn += Wn4[q].x*h4.x + Wn4[q].y*h4.y + Wn4[q].z*h4.z + Wn4[q].w*h4.w;
            }
            #pragma unroll
            for (int dd = 0; dd < 3; ++dd){
                float xv = xsh[cb][r][d0 + dd];
                a_r  += Wxr[dd] * xv;
                a_z  += Wxz[dd] * xv;
                a_xn += Wxn[dd] * xv;
            }
            ar[r] = a_r; az[r] = a_z; ahn[r] = a_hn; axn[r] = a_xn;
        }
        // reduce the two k-halves (lane ^ 32 within the wave)
        #pragma unroll
        for (int r = 0; r < ROWS; ++r){
            ar[r]  += __shfl_xor(ar[r],  32);
            az[r]  += __shfl_xor(az[r],  32);
            ahn[r] += __shfl_xor(ahn[r], 32);
            axn[r] += __shfl_xor(axn[r], 32);
        }
        // finalize: lane (j, kq) updates h[row=kq][j]
        {
            const int r = kq;
            float rg   = fast_sigmoid(ar[r] + bias_r);
            float zg   = fast_sigmoid(az[r] + bias_z);
            float ng   = fast_tanh(axn[r] + bihn + rg * (ahn[r] + bhhn));
            float hold = hbuf[cb][r][j];
            hbuf[cb ^ 1][r][j] = (1.0f - zg) * ng + zg * hold;
        }
        if (tid < ROWS * IN_D) xsh[cb ^ 1][xrow][xd] = xpre;
        __syncthreads();
        cb ^= 1;
    }

    // ================= heads: mu, logvar, z0 =================
    const int zrow = tid >> 4, zi = tid & 15;
    float z0v = 0.0f;
    if (tid < ROWS * LAT){
        float am = mub[zi], al = lvb[zi];
        const float4* pm = (const float4*)(muW + (size_t)zi * HID);
        const float4* pl = (const float4*)(lvW + (size_t)zi * HID);
        const float4* ph = (const float4*)(&hbuf[cb][zrow][0]);
        #pragma unroll
        for (int q = 0; q < 16; ++q){
            float4 wm = pm[q], wl = pl[q], hv = ph[q];
            am += wm.x*hv.x + wm.y*hv.y + wm.z*hv.z + wm.w*hv.w;
            al += wl.x*hv.x + wl.y*hv.y + wl.z*hv.z + wl.w*hv.w;
        }
        const size_t muBase = (size_t)B_TOTAL * T_LEN;
        out[muBase + (size_t)(b0 + zrow) * LAT + zi] = am;
        out[muBase + (size_t)B_TOTAL * LAT + (size_t)(b0 + zrow) * LAT + zi] = al;
        z0v = am + __expf(0.5f * al);   // z0 = mu + sqrt(exp(log_var))
    }

    // ================= ODE: RK4, 24 fixed steps on t in [0,1] =================
    if (tid < ROWS * LAT){
        float ows[16];
        {
            const float4* pw = (const float4*)(oW + (size_t)zi * LAT);
            #pragma unroll
            for (int q = 0; q < 4; ++q){
                float4 w = pw[q];
                ows[4*q+0] = w.x; ows[4*q+1] = w.y; ows[4*q+2] = w.z; ows[4*q+3] = w.w;
            }
        }
        const float obv = ob[zi];
        float z = z0v;
        const float hstep = 1.0f / 24.0f;
        for (int s = 0; s < 24; ++s){
            float y, k1, k2, k3, k4;
            y = z;
            { float acc = obv;
              #pragma unroll
              for (int jj = 0; jj < 16; ++jj){ float yj = __shfl(y, jj, 16); acc = fmaf(ows[jj], yj, acc); }
              k1 = fmaxf(acc, 0.0f); }
            y = z + 0.5f * hstep * k1;
            { float acc = obv;
              #pragma unroll
              for (int jj = 0; jj < 16; ++jj){ float yj = __shfl(y, jj, 16); acc = fmaf(ows[jj], yj, acc); }
              k2 = fmaxf(acc, 0.0f); }
            y = z + 0.5f * hstep * k2;
            { float acc = obv;
              #pragma unroll
              for (int jj = 0; jj < 16; ++jj){ float yj = __shfl(y, jj, 16); acc = fmaf(ows[jj], yj, acc); }
              k3 = fmaxf(acc, 0.0f); }
            y = z + hstep * k3;
            { float acc = obv;
              #pragma unroll
              for (int jj = 0; jj < 16; ++jj){ float yj = __shfl(y, jj, 16); acc = fmaf(ows[jj], yj, acc); }
              k4 = fmaxf(acc, 0.0f); }
            z += (hstep / 6.0f) * (k1 + 2.0f*k2 + 2.0f*k3 + k4);
        }
        zsh[zrow][zi] = z;
    }
    __syncthreads();

    // ================= decoder fc: zd = relu(z @ dfW.T + dfb) =================
    {
        const int row = tid >> 6, o = tid & 63;
        float acc = dfb[o];
        const float4* pw = (const float4*)(dfW + (size_t)o * LAT);
        const float4* pz = (const float4*)(&zsh[row][0]);
        #pragma unroll
        for (int q = 0; q < 4; ++q){
            float4 w = pw[q], zv = pz[q];
            acc += w.x*zv.x + w.y*zv.y + w.z*zv.z + w.w*zv.w;
        }
        zdsh[row][o] = fmaxf(acc, 0.0f);
    }
    __syncthreads();

    // xg_dec = zd @ dec_Wih.T + dec_bih   (3 gates per row, constant over time)
    if (tid < ROWS * 3){
        int row = tid / 3, g = tid % 3;
        float acc = dbih[g];
        const float4* pw = (const float4*)(dWih + (size_t)g * HID);
        const float4* pz = (const float4*)(&zdsh[row][0]);
        #pragma unroll
        for (int q = 0; q < 16; ++q){
            float4 w = pw[q], zv = pz[q];
            acc += w.x*zv.x + w.y*zv.y + w.z*zv.z + w.w*zv.w;
        }
        xgdsh[row][g] = acc;
    }
    __syncthreads();

    // ================= decoder GRU (hidden dim 1), 512 steps =================
    if (tid < ROWS){
        const int row = tid;
        const float xr = xgdsh[row][0], xz = xgdsh[row][1], xn = xgdsh[row][2];
        const float A0 = dWhh[0], A1 = dWhh[1], A2 = dWhh[2];
        const float c0 = dbhh[0], c1 = dbhh[1], c2 = dbhh[2];
        float h = 0.0f;
        for (int t = 0; t < T_LEN; ++t){
            float rr = fast_sigmoid(xr + A0 * h + c0);
            float zz = fast_sigmoid(xz + A1 * h + c1);
            float nn = fast_tanh(xn + rr * (A2 * h + c2));
            h = (1.0f - zz) * nn + zz * h;
            outsh[row][t] = h;
        }
    }
    __syncthreads();

    // coalesced write: rows b0, b0+1 are contiguous in out
    {
        const float4* ps = (const float4*)(&outsh[0][0]);
        float4* pd = (float4*)out;
        const size_t base4 = ((size_t)b0 * T_LEN) >> 2;
        for (int q = tid; q < (ROWS * T_LEN) / 4; q += THREADS)
            pd[base4 + q] = ps[q];
    }
}

extern "C" void kernel_launch(void* const* d_in, const int* in_sizes, int n_in,
                              void* d_out, int out_size, void* d_ws, size_t ws_size,
                              hipStream_t stream){
    glsde_kernel<<<B_TOTAL / ROWS, THREADS, 0, stream>>>(
        (const float*)d_in[0],  (const float*)d_in[1],  (const float*)d_in[2],
        (const float*)d_in[3],  (const float*)d_in[4],  (const float*)d_in[5],
        (const float*)d_in[6],  (const float*)d_in[7],  (const float*)d_in[8],
        (const float*)d_in[9],  (const float*)d_in[10], (const float*)d_in[11],
        (const float*)d_in[12], (const float*)d_in[13], (const float*)d_in[14],
        (const float*)d_in[15], (const float*)d_in[16], (float*)d_out);
}